// Round 1
// baseline (222.226 us; speedup 1.0000x reference)
//
#include <hip/hip_runtime.h>

#define BATCH 32
#define KVLEN 2048
#define HDIM 1024
#define NHEAD 16
#define DHEAD 64
#define FFDIM 4096
#define LN_EPS 1e-5f

// ---------------------------------------------------------------------------
// Generic GEMV over K=1024: out[b][j] = act(dot(in[b,:], W[j,:]) [+bias] [+res])
// One wave handles 4 consecutive j rows; weight fragments persist in registers
// across the 32-batch loop so weights are read exactly once from HBM.
// blockIdx.y = split-K chunk (offsets applied via *_coff params).
// ---------------------------------------------------------------------------
template<bool RELU, bool HAS_BIAS, bool HAS_RES>
__global__ __launch_bounds__(256) void gemv_k1024(
    const float* __restrict__ in, int in_bstride, int in_coff,
    const float* __restrict__ W, int w_jstride, int w_coff,
    const float* __restrict__ bias,
    const float* __restrict__ res, int res_bstride,
    float* __restrict__ out, int out_bstride, int out_coff,
    int nJ)
{
    const int wave = (int)((blockIdx.x * blockDim.x + threadIdx.x) >> 6);
    const int lane = (int)(threadIdx.x & 63);
    const int j0 = wave * 4;
    if (j0 >= nJ) return;
    const int c = (int)blockIdx.y;
    const float* inp = in + (size_t)c * in_coff;
    const float* Wp  = W  + (size_t)c * w_coff;
    float* outp      = out + (size_t)c * out_coff;

    float4 w[4][4];
#pragma unroll
    for (int jj = 0; jj < 4; ++jj) {
        const float4* wr = (const float4*)(Wp + (size_t)(j0 + jj) * w_jstride);
#pragma unroll
        for (int i = 0; i < 4; ++i) w[jj][i] = wr[lane + i * 64];
    }

    for (int b = 0; b < BATCH; ++b) {
        const float4* xr = (const float4*)(inp + (size_t)b * in_bstride);
        float4 xv[4];
#pragma unroll
        for (int i = 0; i < 4; ++i) xv[i] = xr[lane + i * 64];
        float s[4];
#pragma unroll
        for (int jj = 0; jj < 4; ++jj) {
            float a = 0.f;
#pragma unroll
            for (int i = 0; i < 4; ++i)
                a += w[jj][i].x * xv[i].x + w[jj][i].y * xv[i].y
                   + w[jj][i].z * xv[i].z + w[jj][i].w * xv[i].w;
#pragma unroll
            for (int off = 1; off < 64; off <<= 1) a += __shfl_xor(a, off, 64);
            s[jj] = a;
        }
        if (lane == 0) {
            float4 o = make_float4(s[0], s[1], s[2], s[3]);
            if (HAS_BIAS) {
                const float4 bv = *(const float4*)(bias + j0);
                o.x += bv.x; o.y += bv.y; o.z += bv.z; o.w += bv.w;
            }
            if (HAS_RES) {
                const float4 rv = *(const float4*)(res + (size_t)b * res_bstride + j0);
                o.x += rv.x; o.y += rv.y; o.z += rv.z; o.w += rv.w;
            }
            if (RELU) {
                o.x = fmaxf(o.x, 0.f); o.y = fmaxf(o.y, 0.f);
                o.z = fmaxf(o.z, 0.f); o.w = fmaxf(o.w, 0.f);
            }
            *(float4*)(outp + (size_t)b * out_bstride + j0) = o;
        }
    }
}

// ---------------------------------------------------------------------------
// Copy ik/iv slices of qkv to d_out (outputs 1 and 2).
// ---------------------------------------------------------------------------
__global__ __launch_bounds__(256) void copy_ikiv(const float* __restrict__ qkv,
                                                 float* __restrict__ out)
{
    int idx = (int)(blockIdx.x * blockDim.x + threadIdx.x);   // 0..32767
    int b = idx >> 10, j = idx & 1023;
    out[32768 + idx] = qkv[(size_t)b * 3072 + 1024 + j];
    out[65536 + idx] = qkv[(size_t)b * 3072 + 2048 + j];
}

// ---------------------------------------------------------------------------
// Decode attention: one block per (b,h). 1024 threads = 64 groups of 16 lanes.
// Each group streams KV rows (float4/lane = 64 floats = one head row),
// online-softmax accumulates p*V; groups combined through LDS.
// The appended token (row 2048) comes from qkv (ik/iv).
// ---------------------------------------------------------------------------
__global__ __launch_bounds__(1024) void attn_kernel(
    const float* __restrict__ qkv,       // [32][3072]
    const float* __restrict__ k_cache,   // [32][2048][1024]
    const float* __restrict__ v_cache,
    float* __restrict__ attn_out)        // [32][1024]
{
    const int b = (int)(blockIdx.x >> 4);
    const int h = (int)(blockIdx.x & 15);
    const int tid = (int)threadIdx.x;
    const int g  = tid >> 4;     // group 0..63
    const int li = tid & 15;     // lane-in-group

    const float4 q4 = ((const float4*)(qkv + (size_t)b * 3072 + h * DHEAD))[li];
    const float scale = 0.125f;  // 1/sqrt(64)

    float m = -1e30f, l = 0.f;
    float4 acc = make_float4(0.f, 0.f, 0.f, 0.f);

    const float* kbase = k_cache + (size_t)b * KVLEN * HDIM + h * DHEAD;
    const float* vbase = v_cache + (size_t)b * KVLEN * HDIM + h * DHEAD;

    for (int r = g; r < KVLEN; r += 64) {
        const float4 k4 = ((const float4*)(kbase + (size_t)r * HDIM))[li];
        const float4 v4 = ((const float4*)(vbase + (size_t)r * HDIM))[li];
        float s = k4.x * q4.x + k4.y * q4.y + k4.z * q4.z + k4.w * q4.w;
        s += __shfl_xor(s, 1, 64);
        s += __shfl_xor(s, 2, 64);
        s += __shfl_xor(s, 4, 64);
        s += __shfl_xor(s, 8, 64);
        s *= scale;
        const float mn = fmaxf(m, s);
        const float corr = __expf(m - mn);
        const float p = __expf(s - mn);
        l = l * corr + p;
        acc.x = acc.x * corr + p * v4.x;
        acc.y = acc.y * corr + p * v4.y;
        acc.z = acc.z * corr + p * v4.z;
        acc.w = acc.w * corr + p * v4.w;
        m = mn;
    }
    if (g == 0) {  // appended token, row index 2048
        const float4 k4 = ((const float4*)(qkv + (size_t)b * 3072 + 1024 + h * DHEAD))[li];
        const float4 v4 = ((const float4*)(qkv + (size_t)b * 3072 + 2048 + h * DHEAD))[li];
        float s = k4.x * q4.x + k4.y * q4.y + k4.z * q4.z + k4.w * q4.w;
        s += __shfl_xor(s, 1, 64);
        s += __shfl_xor(s, 2, 64);
        s += __shfl_xor(s, 4, 64);
        s += __shfl_xor(s, 8, 64);
        s *= scale;
        const float mn = fmaxf(m, s);
        const float corr = __expf(m - mn);
        const float p = __expf(s - mn);
        l = l * corr + p;
        acc.x = acc.x * corr + p * v4.x;
        acc.y = acc.y * corr + p * v4.y;
        acc.z = acc.z * corr + p * v4.z;
        acc.w = acc.w * corr + p * v4.w;
        m = mn;
    }

    __shared__ float4 sacc4[64][16];
    __shared__ float sm[64], sl[64], sfac[64];
    __shared__ float sL;
    sacc4[g][li] = acc;
    if (li == 0) { sm[g] = m; sl[g] = l; }
    __syncthreads();

    if (tid < 64) {  // wave 0: combine statistics
        const float mg = sm[tid];
        float M = mg;
#pragma unroll
        for (int off = 1; off < 64; off <<= 1) M = fmaxf(M, __shfl_xor(M, off, 64));
        const float fac = __expf(mg - M);
        float L = sl[tid] * fac;
#pragma unroll
        for (int off = 1; off < 64; off <<= 1) L += __shfl_xor(L, off, 64);
        sfac[tid] = fac;
        if (tid == 0) sL = L;
    }
    __syncthreads();

    if (tid < 64) {
        const float* sf = (const float*)sacc4;
        float o = 0.f;
#pragma unroll 8
        for (int gg = 0; gg < 64; ++gg) o += sf[gg * 64 + tid] * sfac[gg];
        attn_out[(size_t)b * HDIM + h * DHEAD + tid] = o / sL;
    }
}

// ---------------------------------------------------------------------------
// Row LayerNorm: 1 block per batch row of 1024.
// ---------------------------------------------------------------------------
__global__ __launch_bounds__(256) void ln_kernel(const float* __restrict__ in,
    const float* __restrict__ w, const float* __restrict__ bv,
    float* __restrict__ out)
{
    const int b = (int)blockIdx.x, tid = (int)threadIdx.x;
    const float4 v = ((const float4*)(in + (size_t)b * HDIM))[tid];
    float sum = v.x + v.y + v.z + v.w;
    float sq  = v.x * v.x + v.y * v.y + v.z * v.z + v.w * v.w;
#pragma unroll
    for (int off = 1; off < 64; off <<= 1) {
        sum += __shfl_xor(sum, off, 64);
        sq  += __shfl_xor(sq,  off, 64);
    }
    __shared__ float s1[4], s2[4];
    const int wid = tid >> 6, lane = tid & 63;
    if (lane == 0) { s1[wid] = sum; s2[wid] = sq; }
    __syncthreads();
    sum = s1[0] + s1[1] + s1[2] + s1[3];
    sq  = s2[0] + s2[1] + s2[2] + s2[3];
    const float mu = sum * (1.f / HDIM);
    const float var = sq * (1.f / HDIM) - mu * mu;
    const float rstd = rsqrtf(var + LN_EPS);
    const float4 wv = ((const float4*)w)[tid];
    const float4 bb = ((const float4*)bv)[tid];
    float4 o;
    o.x = (v.x - mu) * rstd * wv.x + bb.x;
    o.y = (v.y - mu) * rstd * wv.y + bb.y;
    o.z = (v.z - mu) * rstd * wv.z + bb.z;
    o.w = (v.w - mu) * rstd * wv.w + bb.w;
    ((float4*)(out + (size_t)b * HDIM))[tid] = o;
}

// ---------------------------------------------------------------------------
// MLP2 finish: sum 4 split-K partials + bias + residual, then LayerNorm -> d_out
// ---------------------------------------------------------------------------
__global__ __launch_bounds__(256) void mlp2_finish(const float* __restrict__ part,
    const float* __restrict__ x1, const float* __restrict__ mbias,
    const float* __restrict__ w, const float* __restrict__ bv,
    float* __restrict__ out)
{
    const int b = (int)blockIdx.x, tid = (int)threadIdx.x;
    float4 v = make_float4(0.f, 0.f, 0.f, 0.f);
#pragma unroll
    for (int c = 0; c < 4; ++c) {
        const float4 p = ((const float4*)(part + (size_t)c * 32768 + (size_t)b * HDIM))[tid];
        v.x += p.x; v.y += p.y; v.z += p.z; v.w += p.w;
    }
    const float4 r  = ((const float4*)(x1 + (size_t)b * HDIM))[tid];
    const float4 mb = ((const float4*)mbias)[tid];
    v.x += r.x + mb.x; v.y += r.y + mb.y; v.z += r.z + mb.z; v.w += r.w + mb.w;

    float sum = v.x + v.y + v.z + v.w;
    float sq  = v.x * v.x + v.y * v.y + v.z * v.z + v.w * v.w;
#pragma unroll
    for (int off = 1; off < 64; off <<= 1) {
        sum += __shfl_xor(sum, off, 64);
        sq  += __shfl_xor(sq,  off, 64);
    }
    __shared__ float s1[4], s2[4];
    const int wid = tid >> 6, lane = tid & 63;
    if (lane == 0) { s1[wid] = sum; s2[wid] = sq; }
    __syncthreads();
    sum = s1[0] + s1[1] + s1[2] + s1[3];
    sq  = s2[0] + s2[1] + s2[2] + s2[3];
    const float mu = sum * (1.f / HDIM);
    const float var = sq * (1.f / HDIM) - mu * mu;
    const float rstd = rsqrtf(var + LN_EPS);
    const float4 wv = ((const float4*)w)[tid];
    const float4 bb = ((const float4*)bv)[tid];
    float4 o;
    o.x = (v.x - mu) * rstd * wv.x + bb.x;
    o.y = (v.y - mu) * rstd * wv.y + bb.y;
    o.z = (v.z - mu) * rstd * wv.z + bb.z;
    o.w = (v.w - mu) * rstd * wv.w + bb.w;
    ((float4*)(out + (size_t)b * HDIM))[tid] = o;
}

extern "C" void kernel_launch(void* const* d_in, const int* in_sizes, int n_in,
                              void* d_out, int out_size, void* d_ws, size_t ws_size,
                              hipStream_t stream) {
    const float* x     = (const float*)d_in[0];
    const float* kc    = (const float*)d_in[1];
    const float* vc    = (const float*)d_in[2];
    const float* qkvw  = (const float*)d_in[3];
    const float* qkvb  = (const float*)d_in[4];
    const float* outw  = (const float*)d_in[5];
    const float* outb  = (const float*)d_in[6];
    const float* nw1   = (const float*)d_in[7];
    const float* nb1   = (const float*)d_in[8];
    const float* nw2   = (const float*)d_in[9];
    const float* nb2   = (const float*)d_in[10];
    const float* mw1   = (const float*)d_in[11];
    const float* mb1   = (const float*)d_in[12];
    const float* mw2   = (const float*)d_in[13];
    const float* mb2   = (const float*)d_in[14];
    float* out = (float*)d_out;

    float* ws   = (float*)d_ws;
    float* qkv  = ws;            // [32][3072]  = 98304
    float* attn = ws + 98304;    // [32][1024]
    float* y1   = ws + 131072;   // [32][1024]
    float* x1   = ws + 163840;   // [32][1024]
    float* hbuf = ws + 196608;   // [32][4096]  = 131072
    float* part = ws + 327680;   // [4][32][1024]

    // 1) fused QKV projection (writes q, ik, iv into qkv buffer)
    gemv_k1024<false, true, false><<<dim3(192, 1), 256, 0, stream>>>(
        x, HDIM, 0, qkvw, HDIM, 0, qkvb, nullptr, 0, qkv, 3 * HDIM, 0, 3 * HDIM);

    // 2) ik/iv outputs
    copy_ikiv<<<128, 256, 0, stream>>>(qkv, out);

    // 3) attention over KV cache + appended token
    attn_kernel<<<BATCH * NHEAD, 1024, 0, stream>>>(qkv, kc, vc, attn);

    // 4) output projection + residual
    gemv_k1024<false, true, true><<<dim3(64, 1), 256, 0, stream>>>(
        attn, HDIM, 0, outw, HDIM, 0, outb, x, HDIM, y1, HDIM, 0, HDIM);

    // 5) LayerNorm 1
    ln_kernel<<<BATCH, 256, 0, stream>>>(y1, nw1, nb1, x1);

    // 6) MLP up + ReLU
    gemv_k1024<true, true, false><<<dim3(256, 1), 256, 0, stream>>>(
        x1, HDIM, 0, mw1, HDIM, 0, mb1, nullptr, 0, hbuf, FFDIM, 0, FFDIM);

    // 7) MLP down, split-K into 4 deterministic partials
    gemv_k1024<false, false, false><<<dim3(64, 4), 256, 0, stream>>>(
        hbuf, FFDIM, HDIM, mw2, FFDIM, HDIM, nullptr, nullptr, 0,
        part, HDIM, BATCH * HDIM, HDIM);

    // 8) reduce partials + bias + residual + LayerNorm 2 -> x output
    mlp2_finish<<<BATCH, 256, 0, stream>>>(part, x1, mb2, nw2, nb2, out);
}